// Round 10
// baseline (184.293 us; speedup 1.0000x reference)
//
#include <hip/hip_runtime.h>
#include <stdint.h>

#define N_NODES 50000
#define HC 256
#define IN_C 128
#define CAP 64              // padded bucket capacity; deg ~ Poisson(10), max ~30
#define GEMM_BLKS 3125      // 50000/16
#define EPB 160             // edges per gemm block: 3125*160 = 500000

typedef __bf16 v8bf __attribute__((ext_vector_type(8)));
typedef float  v4f  __attribute__((ext_vector_type(4)));

__device__ __forceinline__ uint16_t f2bf(float f) {
    union { float f; uint32_t i; } c; c.f = f;
    uint32_t x = c.i;
    uint32_t r = x + 0x7fffu + ((x >> 16) & 1u);
    return (uint16_t)(r >> 16);
}
__device__ __forceinline__ uint16_t f2h(float f) {
    union { _Float16 h; uint16_t u; } c;
    c.h = (_Float16)f;
    return c.u;
}
__device__ __forceinline__ void h8(uint4 u, float* f) {
    union { uint32_t i; _Float16 h[2]; } c;
    c.i = u.x; f[0] = (float)c.h[0]; f[1] = (float)c.h[1];
    c.i = u.y; f[2] = (float)c.h[0]; f[3] = (float)c.h[1];
    c.i = u.z; f[4] = (float)c.h[0]; f[5] = (float)c.h[1];
    c.i = u.w; f[6] = (float)c.h[0]; f[7] = (float)c.h[1];
}
__device__ __forceinline__ void ld4h(uint2 u, float& f0, float& f1, float& f2, float& f3) {
    union { uint32_t i; _Float16 h[2]; } c;
    c.i = u.x; f0 = (float)c.h[0]; f1 = (float)c.h[1];
    c.i = u.y; f2 = (float)c.h[0]; f3 = (float)c.h[1];
}
// hardware exp2 (v_exp_f32); logits are pre-scaled by log2(e)
__device__ __forceinline__ float hexp2(float x) {
    return __builtin_amdgcn_exp2f(x);
}

// ---- W fp32 [128][256] -> Wt bf16 [256][128]; zero cnt[] ----
__global__ void k_wt(const float* __restrict__ W, uint16_t* __restrict__ Wt,
                     int* __restrict__ cnt) {
    int idx = blockIdx.x * 256 + threadIdx.x;      // 0..32767
    int k = idx >> 8;
    int c = idx & 255;
    Wt[c * IN_C + k] = f2bf(W[idx]);
    if (idx < 25000) *(int2*)(cnt + idx * 2) = make_int2(0, 0);
}

// ---- fused GEMM + in-block fill, v2: no x-staging LDS, single barrier ----
// A-fragment reads x directly from global (L1-resident tile, read 4x);
// LDS = lc only (8.7 KB) -> ~7 blocks/CU instead of 4. Fill unchanged:
// edge loads at entry, atomic+scatter after the epilogue.
__global__ __launch_bounds__(256) void k_gemm_fill(const float* __restrict__ x,
                                                   const uint16_t* __restrict__ Wt,
                                                   const float* __restrict__ att_src,
                                                   const float* __restrict__ att_dst,
                                                   uint16_t* __restrict__ xwh,
                                                   float* __restrict__ a_src,
                                                   float* __restrict__ a_dst,
                                                   const int* __restrict__ src,
                                                   const int* __restrict__ dst,
                                                   int* __restrict__ cnt,
                                                   int* __restrict__ slots,
                                                   int E) {
    __shared__ uint16_t lc[16 * 272];   // fp16 c tile, row stride 272 (pad 16)
    int t  = threadIdx.x;
    int nb = blockIdx.x * 16;

    // ---- issue this block's edge loads early; values park in VGPRs ----
    int e = blockIdx.x * EPB + t;
    bool has = (t < EPB) && (e < E);
    int ed = 0, es = 0;
    if (has) { ed = dst[e]; es = src[e]; }

    int w = t >> 6, lane = t & 63;
    int m = lane & 15, g = lane >> 4;
    v4f acc[4];
#pragma unroll
    for (int ct = 0; ct < 4; ++ct) acc[ct] = (v4f){0.f, 0.f, 0.f, 0.f};
    const float*    xr = x  + (size_t)(nb + m) * IN_C + g * 8;
    const uint16_t* wp = Wt + (size_t)(w * 64 + m) * IN_C + g * 8;
#pragma unroll
    for (int s = 0; s < 4; ++s) {
        float4 p0 = *(const float4*)(xr + s * 32);
        float4 p1 = *(const float4*)(xr + s * 32 + 4);
        v8bf a;
        a[0] = (__bf16)p0.x; a[1] = (__bf16)p0.y; a[2] = (__bf16)p0.z; a[3] = (__bf16)p0.w;
        a[4] = (__bf16)p1.x; a[5] = (__bf16)p1.y; a[6] = (__bf16)p1.z; a[7] = (__bf16)p1.w;
#pragma unroll
        for (int ct = 0; ct < 4; ++ct) {
            v8bf b = *(const v8bf*)(wp + (size_t)ct * 16 * IN_C + s * 32);
            acc[ct] = __builtin_amdgcn_mfma_f32_16x16x32_bf16(a, b, acc[ct], 0, 0, 0);
        }
    }

    // ---- acc -> LDS fp16; XOR-swizzle ct-bits with g (conflict-limited) ----
#pragma unroll
    for (int ct = 0; ct < 4; ++ct) {
        int cols = w * 64 + ((ct ^ g) << 4) + m;   // storage col = logical ^ (g<<4)
#pragma unroll
        for (int r = 0; r < 4; ++r) {
            lc[(g * 4 + r) * 272 + cols] = f2h(acc[ct][r]);
        }
    }
    __syncthreads();                                // single barrier per block

    {
        int row = t >> 4;          // 0..15 ; row>>2 == wave id => shfl stays in-wave
        int c   = t & 15;          // logical 8-col group (of 32 per row)
        int gg  = row >> 2;
        int sc0 = c ^ (gg << 1);
        int sc1 = sc0 + 16;
        const uint16_t* lr = lc + row * 272;
        uint4 u0 = *(const uint4*)(lr + sc0 * 8);
        uint4 u1 = *(const uint4*)(lr + sc1 * 8);
        size_t gb = (size_t)(nb + row) * HC + c * 8;
        *(uint4*)(xwh + gb)       = u0;
        *(uint4*)(xwh + gb + 128) = u1;

        float f0[8], f1[8];
        h8(u0, f0);
        h8(u1, f1);
        float4 as0 = *(const float4*)(att_src + c * 8);
        float4 as1 = *(const float4*)(att_src + c * 8 + 4);
        float4 as2 = *(const float4*)(att_src + 128 + c * 8);
        float4 as3 = *(const float4*)(att_src + 128 + c * 8 + 4);
        float4 ad0 = *(const float4*)(att_dst + c * 8);
        float4 ad1 = *(const float4*)(att_dst + c * 8 + 4);
        float4 ad2 = *(const float4*)(att_dst + 128 + c * 8);
        float4 ad3 = *(const float4*)(att_dst + 128 + c * 8 + 4);

        float ps0 = f0[0]*as0.x + f0[1]*as0.y + f0[2]*as0.z + f0[3]*as0.w
                  + f0[4]*as1.x + f0[5]*as1.y + f0[6]*as1.z + f0[7]*as1.w;
        float pd0 = f0[0]*ad0.x + f0[1]*ad0.y + f0[2]*ad0.z + f0[3]*ad0.w
                  + f0[4]*ad1.x + f0[5]*ad1.y + f0[6]*ad1.z + f0[7]*ad1.w;
        float ps1 = f1[0]*as2.x + f1[1]*as2.y + f1[2]*as2.z + f1[3]*as2.w
                  + f1[4]*as3.x + f1[5]*as3.y + f1[6]*as3.z + f1[7]*as3.w;
        float pd1 = f1[0]*ad2.x + f1[1]*ad2.y + f1[2]*ad2.z + f1[3]*ad2.w
                  + f1[4]*ad3.x + f1[5]*ad3.y + f1[6]*ad3.z + f1[7]*ad3.w;

        ps0 += __shfl_xor(ps0, 1, 64); ps0 += __shfl_xor(ps0, 2, 64);
        ps1 += __shfl_xor(ps1, 1, 64); ps1 += __shfl_xor(ps1, 2, 64);
        pd0 += __shfl_xor(pd0, 1, 64); pd0 += __shfl_xor(pd0, 2, 64);
        pd1 += __shfl_xor(pd1, 1, 64); pd1 += __shfl_xor(pd1, 2, 64);
        if ((c & 3) == 0) {
            // pre-scale by log2(e): k_agg uses hw exp2. Valid through LeakyReLU
            // since fmax(cx, 0.2cx) = c*fmax(x, 0.2x) for c > 0.
            const float LOG2E = 1.44269504f;
            int node = nb + row;
            int h = c >> 2;
            a_src[node * 8 + h]     = ps0 * LOG2E;
            a_src[node * 8 + 4 + h] = ps1 * LOG2E;
            a_dst[node * 8 + h]     = pd0 * LOG2E;
            a_dst[node * 8 + 4 + h] = pd1 * LOG2E;
        }
    }

    // ---- fill: atomics overlap other resident blocks' gemm work ----
    if (has) {
        int pos = atomicAdd(&cnt[ed], 1);
        slots[(size_t)ed * CAP + pos] = es;
    }
}

// ---- aggregation (byte-identical to round 9): v1 layout + 8-deep gather
// ---- pipeline over padded buckets; logits pre-scaled -> hw exp2.
__global__ __launch_bounds__(256) void k_agg(const uint16_t* __restrict__ xwh,
                                             const float* __restrict__ a_src,
                                             const float* __restrict__ a_dst,
                                             const int* __restrict__ cnt,
                                             const int* __restrict__ slots,
                                             const float* __restrict__ bias,
                                             float* __restrict__ out) {
    int i    = blockIdx.x * 4 + (threadIdx.x >> 6);
    int lane = threadIdx.x & 63;
    int h = lane >> 3;
    float sdst = a_dst[i * 8 + h];

    // self loop
    float s0 = a_src[i * 8 + h] + sdst;
    s0 = fmaxf(s0, 0.2f * s0);
    float p0 = hexp2(s0);
    float l = p0;
    uint2 us = *(const uint2*)(xwh + (size_t)i * HC + lane * 4);
    float sx0, sx1, sx2, sx3;
    ld4h(us, sx0, sx1, sx2, sx3);
    float a0 = p0 * sx0, a1 = p0 * sx1, a2 = p0 * sx2, a3 = p0 * sx3;

    int n     = cnt[i];
    int start = i * CAP;
    int end   = start + n;
    int e = start;
    // full rounds: 8 edges, branch-free
    for (; e + 8 <= end; e += 8) {
        uint2 uu[8];
        float sa[8];
#pragma unroll
        for (int k = 0; k < 8; ++k) {
            int j = __builtin_amdgcn_readfirstlane(slots[e + k]);
            uu[k] = *(const uint2*)(xwh + (size_t)j * HC + lane * 4);
            sa[k] = a_src[j * 8 + h];
        }
#pragma unroll
        for (int k = 0; k < 8; ++k) {
            float s = sa[k] + sdst;
            s = fmaxf(s, 0.2f * s);
            float w = hexp2(s);
            l += w;
            float g0, g1, g2, g3;
            ld4h(uu[k], g0, g1, g2, g3);
            a0 = fmaf(w, g0, a0); a1 = fmaf(w, g1, a1);
            a2 = fmaf(w, g2, a2); a3 = fmaf(w, g3, a3);
        }
    }
    // tail round: up to 7 real edges; padded slots are uninitialized -> clamp
    if (e < end) {
        uint2 uu[8];
        float sa[8];
#pragma unroll
        for (int k = 0; k < 8; ++k) {
            int jr = __builtin_amdgcn_readfirstlane(slots[e + k]);
            uint32_t j = min((uint32_t)jr, (uint32_t)(N_NODES - 1));  // clamp garbage
            uu[k] = *(const uint2*)(xwh + (size_t)j * HC + lane * 4);
            sa[k] = a_src[j * 8 + h];
        }
#pragma unroll
        for (int k = 0; k < 8; ++k) {
            float s = sa[k] + sdst;
            s = fmaxf(s, 0.2f * s);
            float w = (e + k < end) ? hexp2(s) : 0.f;
            l += w;
            float g0, g1, g2, g3;
            ld4h(uu[k], g0, g1, g2, g3);
            a0 = fmaf(w, g0, a0); a1 = fmaf(w, g1, a1);
            a2 = fmaf(w, g2, a2); a3 = fmaf(w, g3, a3);
        }
    }

    float inv = 1.f / (l + 1e-16f);
    float4 b = *(const float4*)(bias + lane * 4);
    float4 o;
    o.x = fmaf(a0, inv, b.x);
    o.y = fmaf(a1, inv, b.y);
    o.z = fmaf(a2, inv, b.z);
    o.w = fmaf(a3, inv, b.w);
    *(float4*)(out + (size_t)i * HC + lane * 4) = o;
}

extern "C" void kernel_launch(void* const* d_in, const int* in_sizes, int n_in,
                              void* d_out, int out_size, void* d_ws, size_t ws_size,
                              hipStream_t stream) {
    const float* x       = (const float*)d_in[0];
    const int*   ei      = (const int*)d_in[1];
    const float* W       = (const float*)d_in[2];
    const float* att_src = (const float*)d_in[3];
    const float* att_dst = (const float*)d_in[4];
    const float* bias    = (const float*)d_in[5];
    float*       out     = (float*)d_out;

    const int E = in_sizes[1] / 2;
    const int* src = ei;        // (2,E) int32 row-major — verified r9
    const int* dst = ei + E;

    char* ws = (char*)d_ws;
    uint16_t* xwh   = (uint16_t*)(ws);                         // 25,600,000 B
    uint16_t* Wt    = (uint16_t*)(ws + 25600000);              //     65,536 B
    float*    a_src = (float*)   (ws + 25665536);              //  1,600,000 B
    float*    a_dst = (float*)   (ws + 27265536);              //  1,600,000 B
    int*      cnt   = (int*)     (ws + 28865536);              //    200,000 B
    int*      slots = (int*)     (ws + 29065536);              // 12,800,000 B (50000*64 ints)
    // high-water: 41,865,536 B (< 82.7 MB proven available)

    k_wt<<<128, 256, 0, stream>>>(W, Wt, cnt);
    k_gemm_fill<<<GEMM_BLKS, 256, 0, stream>>>(x, Wt, att_src, att_dst,
                                               xwh, a_src, a_dst,
                                               src, dst, cnt, slots, E);
    k_agg<<<12500, 256, 0, stream>>>(xwh, a_src, a_dst, cnt, slots, bias, out);
}

// Round 11
// 174.478 us; speedup vs baseline: 1.0563x; 1.0563x over previous
//
#include <hip/hip_runtime.h>
#include <stdint.h>

#define N_NODES 50000
#define HC 256
#define IN_C 128
#define CAP 64              // padded bucket capacity; deg ~ Poisson(10), max ~30
#define GEMM_BLKS 3125      // 50000/16
#define EPB 160             // edges per gemm block: 3125*160 = 500000

typedef __bf16 v8bf __attribute__((ext_vector_type(8)));
typedef float  v4f  __attribute__((ext_vector_type(4)));

__device__ __forceinline__ uint16_t f2bf(float f) {
    union { float f; uint32_t i; } c; c.f = f;
    uint32_t x = c.i;
    uint32_t r = x + 0x7fffu + ((x >> 16) & 1u);
    return (uint16_t)(r >> 16);
}
__device__ __forceinline__ uint16_t f2h(float f) {
    union { _Float16 h; uint16_t u; } c;
    c.h = (_Float16)f;
    return c.u;
}
__device__ __forceinline__ void h8(uint4 u, float* f) {
    union { uint32_t i; _Float16 h[2]; } c;
    c.i = u.x; f[0] = (float)c.h[0]; f[1] = (float)c.h[1];
    c.i = u.y; f[2] = (float)c.h[0]; f[3] = (float)c.h[1];
    c.i = u.z; f[4] = (float)c.h[0]; f[5] = (float)c.h[1];
    c.i = u.w; f[6] = (float)c.h[0]; f[7] = (float)c.h[1];
}
__device__ __forceinline__ void ld4h(uint2 u, float& f0, float& f1, float& f2, float& f3) {
    union { uint32_t i; _Float16 h[2]; } c;
    c.i = u.x; f0 = (float)c.h[0]; f1 = (float)c.h[1];
    c.i = u.y; f2 = (float)c.h[0]; f3 = (float)c.h[1];
}
// hardware exp2 (v_exp_f32); logits are pre-scaled by log2(e)
__device__ __forceinline__ float hexp2(float x) {
    return __builtin_amdgcn_exp2f(x);
}

// ---- W fp32 [128][256] -> Wt bf16 [256][128]; zero cnt[] ----
__global__ void k_wt(const float* __restrict__ W, uint16_t* __restrict__ Wt,
                     int* __restrict__ cnt) {
    int idx = blockIdx.x * 256 + threadIdx.x;      // 0..32767
    int k = idx >> 8;
    int c = idx & 255;
    Wt[c * IN_C + k] = f2bf(W[idx]);
    if (idx < 25000) *(int2*)(cnt + idx * 2) = make_int2(0, 0);
}

// ---- fused GEMM + in-block fill, v3: round-9 data path, UNION LDS ----
// lx (x-stage, 4.3 KB) and lc (c-stage, 8.7 KB) are never live at the same
// time -> share one 8.7 KB buffer (was 13.3 KB) -> 7 blocks/CU in the 64 KB
// workgroup-LDS pool instead of 4. Costs one extra barrier between the last
// lx read (MFMA loop) and the first lc write.
__global__ __launch_bounds__(256) void k_gemm_fill(const float* __restrict__ x,
                                                   const uint16_t* __restrict__ Wt,
                                                   const float* __restrict__ att_src,
                                                   const float* __restrict__ att_dst,
                                                   uint16_t* __restrict__ xwh,
                                                   float* __restrict__ a_src,
                                                   float* __restrict__ a_dst,
                                                   const int* __restrict__ src,
                                                   const int* __restrict__ dst,
                                                   int* __restrict__ cnt,
                                                   int* __restrict__ slots,
                                                   int E) {
    __shared__ uint16_t lsm[16 * 272];  // 8704 B union: lx (stride 136) / lc (stride 272)
    uint16_t* lx = lsm;
    uint16_t* lc = lsm;
    int t  = threadIdx.x;
    int nb = blockIdx.x * 16;

    // ---- issue this block's edge loads early; values park in VGPRs ----
    int e = blockIdx.x * EPB + t;
    bool has = (t < EPB) && (e < E);
    int ed = 0, es = 0;
    if (has) { ed = dst[e]; es = src[e]; }

    // ---- stage x -> LDS bf16 (each thread: 8 floats, coalesced) ----
    {
        int row = t >> 4, c8 = (t & 15) * 8;
        const float4* p = (const float4*)(x + (size_t)(nb + row) * IN_C + c8);
        float4 p0 = p[0], p1 = p[1];
        v8bf a;
        a[0] = (__bf16)p0.x; a[1] = (__bf16)p0.y; a[2] = (__bf16)p0.z; a[3] = (__bf16)p0.w;
        a[4] = (__bf16)p1.x; a[5] = (__bf16)p1.y; a[6] = (__bf16)p1.z; a[7] = (__bf16)p1.w;
        *(v8bf*)(lx + row * 136 + c8) = a;
    }
    __syncthreads();                               // barrier 1: lx ready

    int w = t >> 6, lane = t & 63;
    int m = lane & 15, g = lane >> 4;
    v4f acc[4];
#pragma unroll
    for (int ct = 0; ct < 4; ++ct) acc[ct] = (v4f){0.f, 0.f, 0.f, 0.f};
    const uint16_t* lxp = lx + m * 136 + g * 8;
    const uint16_t* wp  = Wt + (size_t)(w * 64 + m) * IN_C + g * 8;
#pragma unroll
    for (int s = 0; s < 4; ++s) {
        v8bf a = *(const v8bf*)(lxp + s * 32);
#pragma unroll
        for (int ct = 0; ct < 4; ++ct) {
            v8bf b = *(const v8bf*)(wp + (size_t)ct * 16 * IN_C + s * 32);
            acc[ct] = __builtin_amdgcn_mfma_f32_16x16x32_bf16(a, b, acc[ct], 0, 0, 0);
        }
    }
    __syncthreads();                               // barrier 2: lx reads done, lc may overwrite

    // ---- acc -> LDS fp16; XOR-swizzle ct-bits with g ----
#pragma unroll
    for (int ct = 0; ct < 4; ++ct) {
        int cols = w * 64 + ((ct ^ g) << 4) + m;   // storage col = logical ^ (g<<4)
#pragma unroll
        for (int r = 0; r < 4; ++r) {
            lc[(g * 4 + r) * 272 + cols] = f2h(acc[ct][r]);
        }
    }
    __syncthreads();                               // barrier 3: lc ready

    {
        int row = t >> 4;          // 0..15 ; row>>2 == wave id => shfl stays in-wave
        int c   = t & 15;          // logical 8-col group (of 32 per row)
        int gg  = row >> 2;
        int sc0 = c ^ (gg << 1);
        int sc1 = sc0 + 16;
        const uint16_t* lr = lc + row * 272;
        uint4 u0 = *(const uint4*)(lr + sc0 * 8);
        uint4 u1 = *(const uint4*)(lr + sc1 * 8);
        size_t gb = (size_t)(nb + row) * HC + c * 8;
        *(uint4*)(xwh + gb)       = u0;
        *(uint4*)(xwh + gb + 128) = u1;

        float f0[8], f1[8];
        h8(u0, f0);
        h8(u1, f1);
        float4 as0 = *(const float4*)(att_src + c * 8);
        float4 as1 = *(const float4*)(att_src + c * 8 + 4);
        float4 as2 = *(const float4*)(att_src + 128 + c * 8);
        float4 as3 = *(const float4*)(att_src + 128 + c * 8 + 4);
        float4 ad0 = *(const float4*)(att_dst + c * 8);
        float4 ad1 = *(const float4*)(att_dst + c * 8 + 4);
        float4 ad2 = *(const float4*)(att_dst + 128 + c * 8);
        float4 ad3 = *(const float4*)(att_dst + 128 + c * 8 + 4);

        float ps0 = f0[0]*as0.x + f0[1]*as0.y + f0[2]*as0.z + f0[3]*as0.w
                  + f0[4]*as1.x + f0[5]*as1.y + f0[6]*as1.z + f0[7]*as1.w;
        float pd0 = f0[0]*ad0.x + f0[1]*ad0.y + f0[2]*ad0.z + f0[3]*ad0.w
                  + f0[4]*ad1.x + f0[5]*ad1.y + f0[6]*ad1.z + f0[7]*ad1.w;
        float ps1 = f1[0]*as2.x + f1[1]*as2.y + f1[2]*as2.z + f1[3]*as2.w
                  + f1[4]*as3.x + f1[5]*as3.y + f1[6]*as3.z + f1[7]*as3.w;
        float pd1 = f1[0]*ad2.x + f1[1]*ad2.y + f1[2]*ad2.z + f1[3]*ad2.w
                  + f1[4]*ad3.x + f1[5]*ad3.y + f1[6]*ad3.z + f1[7]*ad3.w;

        ps0 += __shfl_xor(ps0, 1, 64); ps0 += __shfl_xor(ps0, 2, 64);
        ps1 += __shfl_xor(ps1, 1, 64); ps1 += __shfl_xor(ps1, 2, 64);
        pd0 += __shfl_xor(pd0, 1, 64); pd0 += __shfl_xor(pd0, 2, 64);
        pd1 += __shfl_xor(pd1, 1, 64); pd1 += __shfl_xor(pd1, 2, 64);
        if ((c & 3) == 0) {
            // pre-scale by log2(e): k_agg uses hw exp2. Valid through LeakyReLU
            // since fmax(cx, 0.2cx) = c*fmax(x, 0.2x) for c > 0.
            const float LOG2E = 1.44269504f;
            int node = nb + row;
            int h = c >> 2;
            a_src[node * 8 + h]     = ps0 * LOG2E;
            a_src[node * 8 + 4 + h] = ps1 * LOG2E;
            a_dst[node * 8 + h]     = pd0 * LOG2E;
            a_dst[node * 8 + 4 + h] = pd1 * LOG2E;
        }
    }

    // ---- fill: atomics overlap other resident blocks' gemm work ----
    if (has) {
        int pos = atomicAdd(&cnt[ed], 1);
        slots[(size_t)ed * CAP + pos] = es;
    }
}

// ---- aggregation (byte-identical to round 9): v1 layout + 8-deep gather
// ---- pipeline over padded buckets; logits pre-scaled -> hw exp2.
__global__ __launch_bounds__(256) void k_agg(const uint16_t* __restrict__ xwh,
                                             const float* __restrict__ a_src,
                                             const float* __restrict__ a_dst,
                                             const int* __restrict__ cnt,
                                             const int* __restrict__ slots,
                                             const float* __restrict__ bias,
                                             float* __restrict__ out) {
    int i    = blockIdx.x * 4 + (threadIdx.x >> 6);
    int lane = threadIdx.x & 63;
    int h = lane >> 3;
    float sdst = a_dst[i * 8 + h];

    // self loop
    float s0 = a_src[i * 8 + h] + sdst;
    s0 = fmaxf(s0, 0.2f * s0);
    float p0 = hexp2(s0);
    float l = p0;
    uint2 us = *(const uint2*)(xwh + (size_t)i * HC + lane * 4);
    float sx0, sx1, sx2, sx3;
    ld4h(us, sx0, sx1, sx2, sx3);
    float a0 = p0 * sx0, a1 = p0 * sx1, a2 = p0 * sx2, a3 = p0 * sx3;

    int n     = cnt[i];
    int start = i * CAP;
    int end   = start + n;
    int e = start;
    // full rounds: 8 edges, branch-free
    for (; e + 8 <= end; e += 8) {
        uint2 uu[8];
        float sa[8];
#pragma unroll
        for (int k = 0; k < 8; ++k) {
            int j = __builtin_amdgcn_readfirstlane(slots[e + k]);
            uu[k] = *(const uint2*)(xwh + (size_t)j * HC + lane * 4);
            sa[k] = a_src[j * 8 + h];
        }
#pragma unroll
        for (int k = 0; k < 8; ++k) {
            float s = sa[k] + sdst;
            s = fmaxf(s, 0.2f * s);
            float w = hexp2(s);
            l += w;
            float g0, g1, g2, g3;
            ld4h(uu[k], g0, g1, g2, g3);
            a0 = fmaf(w, g0, a0); a1 = fmaf(w, g1, a1);
            a2 = fmaf(w, g2, a2); a3 = fmaf(w, g3, a3);
        }
    }
    // tail round: up to 7 real edges; padded slots are uninitialized -> clamp
    if (e < end) {
        uint2 uu[8];
        float sa[8];
#pragma unroll
        for (int k = 0; k < 8; ++k) {
            int jr = __builtin_amdgcn_readfirstlane(slots[e + k]);
            uint32_t j = min((uint32_t)jr, (uint32_t)(N_NODES - 1));  // clamp garbage
            uu[k] = *(const uint2*)(xwh + (size_t)j * HC + lane * 4);
            sa[k] = a_src[j * 8 + h];
        }
#pragma unroll
        for (int k = 0; k < 8; ++k) {
            float s = sa[k] + sdst;
            s = fmaxf(s, 0.2f * s);
            float w = (e + k < end) ? hexp2(s) : 0.f;
            l += w;
            float g0, g1, g2, g3;
            ld4h(uu[k], g0, g1, g2, g3);
            a0 = fmaf(w, g0, a0); a1 = fmaf(w, g1, a1);
            a2 = fmaf(w, g2, a2); a3 = fmaf(w, g3, a3);
        }
    }

    float inv = 1.f / (l + 1e-16f);
    float4 b = *(const float4*)(bias + lane * 4);
    float4 o;
    o.x = fmaf(a0, inv, b.x);
    o.y = fmaf(a1, inv, b.y);
    o.z = fmaf(a2, inv, b.z);
    o.w = fmaf(a3, inv, b.w);
    *(float4*)(out + (size_t)i * HC + lane * 4) = o;
}

extern "C" void kernel_launch(void* const* d_in, const int* in_sizes, int n_in,
                              void* d_out, int out_size, void* d_ws, size_t ws_size,
                              hipStream_t stream) {
    const float* x       = (const float*)d_in[0];
    const int*   ei      = (const int*)d_in[1];
    const float* W       = (const float*)d_in[2];
    const float* att_src = (const float*)d_in[3];
    const float* att_dst = (const float*)d_in[4];
    const float* bias    = (const float*)d_in[5];
    float*       out     = (float*)d_out;

    const int E = in_sizes[1] / 2;
    const int* src = ei;        // (2,E) int32 row-major — verified r9
    const int* dst = ei + E;

    char* ws = (char*)d_ws;
    uint16_t* xwh   = (uint16_t*)(ws);                         // 25,600,000 B
    uint16_t* Wt    = (uint16_t*)(ws + 25600000);              //     65,536 B
    float*    a_src = (float*)   (ws + 25665536);              //  1,600,000 B
    float*    a_dst = (float*)   (ws + 27265536);              //  1,600,000 B
    int*      cnt   = (int*)     (ws + 28865536);              //    200,000 B
    int*      slots = (int*)     (ws + 29065536);              // 12,800,000 B (50000*64 ints)
    // high-water: 41,865,536 B (< 82.7 MB proven available)

    k_wt<<<128, 256, 0, stream>>>(W, Wt, cnt);
    k_gemm_fill<<<GEMM_BLKS, 256, 0, stream>>>(x, Wt, att_src, att_dst,
                                               xwh, a_src, a_dst,
                                               src, dst, cnt, slots, E);
    k_agg<<<12500, 256, 0, stream>>>(xwh, a_src, a_dst, cnt, slots, bias, out);
}